// Round 2
// 294.977 us; speedup vs baseline: 1.0459x; 1.0459x over previous
//
#include <hip/hip_runtime.h>
#include <hip/hip_bf16.h>

// Problem constants (B=2, T=2048, C=2048, NH=16, L=128)
#define B_   2
#define T_   2048
#define C_   2048
#define NH_  16
#define L_   128
#define NKQ  2176   // L_ + NH_*L_
#define MTOK 4096   // B_*T_
#define SCALE_ 0.08838834764831845f           // 1/sqrt(128)
#define SCALE2_ 0.12753785792696073f          // SCALE_ * log2(e)

typedef short short8 __attribute__((ext_vector_type(8)));
typedef float f32x4  __attribute__((ext_vector_type(4)));

// async global->LDS, 16B per lane; LDS base must be wave-uniform.
#define GLD16(gp, lp) __builtin_amdgcn_global_load_lds(                      \
    (const __attribute__((address_space(1))) void*)(gp),                     \
    (__attribute__((address_space(3))) void*)(lp), 16, 0, 0)

__device__ __forceinline__ unsigned short f2bf(float f) {
  union { float f; unsigned u; } x; x.f = f;
  unsigned r = x.u + 0x7fffu + ((x.u >> 16) & 1u);   // RNE
  return (unsigned short)(r >> 16);
}

// ---------------- merged prep: cvt + 3 weight transposes + bias concat ----------------
// One dispatch instead of 5 (saves 4 graph launch gaps). Branch is block-uniform.
// grid = 8192 (cvt) + 256 (W_lat) + 4096 (W_d) + 4096 (W_proj) + 9 (bias) = 16649
__global__ __launch_bounds__(256) void prep_all(
    const float* __restrict__ x, const float* __restrict__ W_lat,
    const float* __restrict__ W_d, const float* __restrict__ W_proj,
    const float* __restrict__ b_lat, const float* __restrict__ b_d,
    unsigned short* __restrict__ x_bf, unsigned short* __restrict__ BtCat,
    unsigned short* __restrict__ WprojT, float* __restrict__ biascat) {
  __shared__ float tile[32][33];
  int bid = blockIdx.x;
  const int tid = threadIdx.x;

  if (bid < 8192) {                       // x fp32 -> bf16, 4 elems/thread
    int i = bid * 1024 + tid * 4;
    float4 v = *(const float4*)(x + i);
    ushort4 o;
    o.x = f2bf(v.x); o.y = f2bf(v.y); o.z = f2bf(v.z); o.w = f2bf(v.w);
    *(ushort4*)(x_bf + i) = o;
    return;
  }
  bid -= 8192;

  const float* W; unsigned short* Wt; int K, N; float mul; int nbx;
  if (bid < 256) {                        // W_lat [C][L] -> BtCat[0:L][C]
    W = W_lat; Wt = BtCat; K = C_; N = L_; mul = 1.f; nbx = 4;
  } else if (bid < 256 + 4096) {          // W_d [C][2048] -> BtCat[L:][C], fold scale*log2e
    bid -= 256;
    W = W_d; Wt = BtCat + (size_t)L_ * C_; K = C_; N = NH_ * L_; mul = SCALE2_; nbx = 64;
  } else if (bid < 256 + 8192) {          // W_proj [2048][C] -> WprojT[C][2048]
    bid -= 256 + 4096;
    W = W_proj; Wt = WprojT; K = NH_ * L_; N = C_; mul = 1.f; nbx = 64;
  } else {                                // bias concat [b_lat | scale*log2e*b_d]
    int i = (bid - (256 + 8192)) * 256 + tid;
    if (i < L_) biascat[i] = b_lat[i];
    else if (i < NKQ) biascat[i] = b_d[i - L_] * SCALE2_;
    return;
  }

  const int bx = (bid % nbx) * 32, by = (bid / nbx) * 32;
  const int tx = tid & 31, ty = tid >> 5;
  #pragma unroll
  for (int i2 = 0; i2 < 4; i2++)
    tile[ty + i2 * 8][tx] = W[(size_t)(by + ty + i2 * 8) * N + bx + tx];
  __syncthreads();
  #pragma unroll
  for (int i2 = 0; i2 < 4; i2++)
    Wt[(size_t)(bx + ty + i2 * 8) * K + by + tx] = f2bf(tile[tx][ty + i2 * 8] * mul);
}

// ---- transpose latent cols of kq -> KlT[b][l][t] (bf16) ----
__global__ void transpose_lat(const unsigned short* __restrict__ kq,
                              unsigned short* __restrict__ KlT) {
  __shared__ unsigned short tile[32][33];
  int t0 = blockIdx.x * 32, l0 = blockIdx.y * 32, b = blockIdx.z;
  int tx = threadIdx.x, ty = threadIdx.y;
  #pragma unroll
  for (int i = 0; i < 4; i++)
    tile[ty + i * 8][tx] = kq[((size_t)b * T_ + t0 + ty + i * 8) * NKQ + l0 + tx];
  __syncthreads();
  #pragma unroll
  for (int i = 0; i < 4; i++)
    KlT[((size_t)b * L_ + l0 + ty + i * 8) * T_ + t0 + tx] = tile[tx][ty + i * 8];
}

// ---------------- bf16 MFMA GEMM (m97 structure):  C = A @ Bt^T + bias ----------------
__global__ __launch_bounds__(256) void gemm_bt_bias(
    const unsigned short* __restrict__ A,   // [M][K] bf16
    const unsigned short* __restrict__ Bt,  // [N][K] bf16
    const float* __restrict__ bias,         // [N]
    unsigned short* __restrict__ Cb,        // bf16 out (or null)
    float* __restrict__ Cf,                 // fp32 out (or null)
    int M, int N, int K) {
  __shared__ __align__(16) unsigned short As[128 * 32];  // unpadded, BK=32
  __shared__ __align__(16) unsigned short Bs[128 * 32];
  const int tid  = threadIdx.x;
  const int wave = tid >> 6, lane = tid & 63;
  const int lcol = lane & 15, quad = lane >> 4;
  const int m0 = blockIdx.x * 128, n0 = blockIdx.y * 128;
  const int wm = (wave >> 1) * 64, wn = (wave & 1) * 64;
  const int lrow = lane >> 2, lchunk = (lane & 3) * 8;

  f32x4 acc[4][4];
  #pragma unroll
  for (int i = 0; i < 4; i++)
    #pragma unroll
    for (int j = 0; j < 4; j++) acc[i][j] = (f32x4){0.f, 0.f, 0.f, 0.f};

  for (int kc = 0; kc < K; kc += 32) {
    __syncthreads();
    {
      int rb = wave * 32;
      GLD16(&A [(size_t)(m0 + rb      + lrow) * K + kc + lchunk], &As[ rb       * 32]);
      GLD16(&A [(size_t)(m0 + rb + 16 + lrow) * K + kc + lchunk], &As[(rb + 16) * 32]);
      GLD16(&Bt[(size_t)(n0 + rb      + lrow) * K + kc + lchunk], &Bs[ rb       * 32]);
      GLD16(&Bt[(size_t)(n0 + rb + 16 + lrow) * K + kc + lchunk], &Bs[(rb + 16) * 32]);
    }
    __syncthreads();
    short8 af[4], bfr[4];
    #pragma unroll
    for (int i = 0; i < 4; i++)
      af[i] = *(const short8*)&As[(wm + i * 16 + lcol) * 32 + quad * 8];
    #pragma unroll
    for (int j = 0; j < 4; j++)
      bfr[j] = *(const short8*)&Bs[(wn + j * 16 + lcol) * 32 + quad * 8];
    #pragma unroll
    for (int i = 0; i < 4; i++)
      #pragma unroll
      for (int j = 0; j < 4; j++)
        acc[i][j] = __builtin_amdgcn_mfma_f32_16x16x32_bf16(af[i], bfr[j], acc[i][j], 0, 0, 0);
  }

  #pragma unroll
  for (int i = 0; i < 4; i++) {
    #pragma unroll
    for (int j = 0; j < 4; j++) {
      int col = n0 + wn + j * 16 + lcol;
      float bv = bias[col];
      #pragma unroll
      for (int r = 0; r < 4; r++) {
        int row = m0 + wm + i * 16 + quad * 4 + r;
        float v = acc[i][j][r] + bv;
        if (Cf) Cf[(size_t)row * N + col] = v;
        else    Cb[(size_t)row * N + col] = f2bf(v);
      }
    }
  }
}

// ---------------- fused causal MLA attention (double-buffered K staging) ----------------
// Block: 4 waves = 4 heads, 32 q-rows. s-tiles of 64, K tiles double-buffered:
//   stage(0); loop: barrier; stage(ts+1 -> other buf); compute(ts)
// so the barrier's vmcnt drain waits on loads issued a full compute-phase ago.
// NOTE (R4 bug): the staging swizzle XOR must use the ACTUAL row&7 of each
// sub-load (rows differ by 4 between kk's) — compute it per kk, don't hoist.
// Grid 512: n<256 heavy tile (63-qi), n>=256 light (qi) -> heavy+light pair per CU.
// No-max softmax; scale*log2e folded into q; exp via v_exp2.
// R5: grid caps occupancy at 8 waves/CU (2048 waves total) -> latency-bound on the
// serial per-tile chain. Fix: (a) split softmax+PV by s-halves so half-1's exp2/pack
// VALU overlaps half-0's PV MFMA drain (also shortens P-write -> pa-read lgkm wait;
// Kt bfrag sharing across i preserved); (b) s_setprio(1) around MFMA clusters (T5).
// Register growth is free: 2 waves/SIMD grid cap leaves ~256 VGPR/wave budget.
__global__ __launch_bounds__(256, 2) void attn_mla(
    const unsigned short* __restrict__ kq,   // [B*T][NKQ]
    const unsigned short* __restrict__ KlT,  // [B][L][T]
    unsigned short* __restrict__ y) {        // [B*T][NH*L]
  __shared__ __align__(16) unsigned short Kr[2][64 * 128];   // [s][l] swizzled
  __shared__ __align__(16) unsigned short Kt[2][128 * 64];   // [l][s] swizzled
  __shared__ __align__(16) unsigned short Pls[4][32 * 64];   // per-wave P, swizzled

  const int tid  = threadIdx.x;
  const int wave = tid >> 6, lane = tid & 63;
  const int lcol = lane & 15, quad = lane >> 4;
  const int n    = blockIdx.x;
  const int slot = n >> 8, c = n & 255;
  const int hg   = c >> 5, qi = c & 31;
  const int b    = hg >> 2;
  const int h    = (hg & 3) * 4 + wave;
  const int qt32 = slot ? qi : (63 - qi);    // 32-row q-tile index
  const size_t rowbase = (size_t)b * T_;
  const int q0 = qt32 * 32;
  unsigned short* Pw = &Pls[wave][0];

  // Q fragments (A-layout m=lane&15, k=quad*8+j); scale*log2e pre-folded
  short8 qf[2][4];
  #pragma unroll
  for (int i = 0; i < 2; i++) {
    const unsigned short* qp = kq + (rowbase + q0 + i * 16 + lcol) * NKQ + L_ + h * L_;
    #pragma unroll
    for (int kc = 0; kc < 4; kc++)
      qf[i][kc] = *(const short8*)(qp + kc * 32 + quad * 8);
  }

  f32x4 acco[2][8];
  #pragma unroll
  for (int i = 0; i < 2; i++)
    #pragma unroll
    for (int ns = 0; ns < 8; ns++) acco[i][ns] = (f32x4){0.f, 0.f, 0.f, 0.f};
  float lsum[2][4];
  #pragma unroll
  for (int i = 0; i < 2; i++)
    #pragma unroll
    for (int r = 0; r < 4; r++) lsum[i][r] = 0.f;

  const int nt = (qt32 >> 1) + 1;

  // prologue: stage tile 0 into buffer 0 (swizzle computed per sub-load!)
  #pragma unroll
  for (int kk = 0; kk < 4; kk++) {
    int r0 = wave * 16 + kk * 4;
    int rg = r0 + (lane >> 4);
    int cl = ((lane & 15) ^ (rg & 7)) * 8;
    GLD16(kq + (rowbase + rg) * NKQ + cl, &Kr[0][r0 * 128]);
  }
  #pragma unroll
  for (int kk = 0; kk < 4; kk++) {
    int r0 = wave * 32 + kk * 8;
    int rg = r0 + (lane >> 3);
    int cl = ((lane & 7) ^ (rg & 7)) * 8;
    GLD16(KlT + ((size_t)b * L_ + rg) * T_ + cl, &Kt[0][r0 * 64]);
  }

  for (int ts = 0; ts < nt; ts++) {
    const int cur = ts & 1;
    __syncthreads();  // drains stage(ts) [issued one full phase ago] + guards buf reuse

    if (ts + 1 < nt) {  // prefetch next tile into the other buffer
      const int s1 = (ts + 1) * 64;
      #pragma unroll
      for (int kk = 0; kk < 4; kk++) {
        int r0 = wave * 16 + kk * 4;
        int rg = r0 + (lane >> 4);
        int cl = ((lane & 15) ^ (rg & 7)) * 8;
        GLD16(kq + (rowbase + s1 + rg) * NKQ + cl, &Kr[cur ^ 1][r0 * 128]);
      }
      #pragma unroll
      for (int kk = 0; kk < 4; kk++) {
        int r0 = wave * 32 + kk * 8;
        int rg = r0 + (lane >> 3);
        int cl = ((lane & 7) ^ (rg & 7)) * 8;
        GLD16(KlT + ((size_t)b * L_ + rg) * T_ + s1 + cl, &Kt[cur ^ 1][r0 * 64]);
      }
    }

    const unsigned short* Krc = &Kr[cur][0];
    const unsigned short* Ktc = &Kt[cur][0];

    // S(32x64) = Q @ K^T
    f32x4 accs[2][4];
    #pragma unroll
    for (int i = 0; i < 2; i++)
      #pragma unroll
      for (int ns = 0; ns < 4; ns++) accs[i][ns] = (f32x4){0.f, 0.f, 0.f, 0.f};
    __builtin_amdgcn_s_setprio(1);
    #pragma unroll
    for (int kc = 0; kc < 4; kc++)
      #pragma unroll
      for (int ns = 0; ns < 4; ns++) {
        short8 bfrag = *(const short8*)&Krc[(ns * 16 + lcol) * 128 +
                                            (((kc * 4 + quad) ^ (lcol & 7)) * 8)];
        #pragma unroll
        for (int i = 0; i < 2; i++)
          accs[i][ns] = __builtin_amdgcn_mfma_f32_16x16x32_bf16(qf[i][kc], bfrag, accs[i][ns], 0, 0, 0);
      }
    __builtin_amdgcn_s_setprio(0);

    // p = 2^s (log2e folded); truncate to bf16, lsum from truncated value.
    // Split into s-halves: softmax(half) then PV(kc2=half) — half-1 VALU overlaps
    // half-0's PV MFMA drain (separate pipes), and the P->pa lgkm wait shortens.
    const bool diag = (ts == nt - 1);
    #pragma unroll
    for (int half = 0; half < 2; half++) {
      #pragma unroll
      for (int i = 0; i < 2; i++)
        #pragma unroll
        for (int n2 = 0; n2 < 2; n2++) {
          const int ns = half * 2 + n2;
          #pragma unroll
          for (int r = 0; r < 4; r++) {
            float v = accs[i][ns][r];
            int sg = ns * 16 + lcol;
            int qg = (qt32 & 1) * 32 + i * 16 + quad * 4 + r;
            if (diag && sg > qg) v = -1e30f;
            float e = __builtin_amdgcn_exp2f(v);
            unsigned eu = __float_as_uint(e) & 0xffff0000u;
            lsum[i][r] += __uint_as_float(eu);
            int row = i * 16 + quad * 4 + r;
            int col = ns * 16 + lcol;
            int phys = ((col >> 3) ^ (row & 7));
            Pw[row * 64 + phys * 8 + (col & 7)] = (unsigned short)(eu >> 16);
          }
        }

      // O(32x128) += P(32x[half]) @ K([half]x128)   (Pw wave-private: no barrier)
      short8 pa[2];
      #pragma unroll
      for (int i = 0; i < 2; i++)
        pa[i] = *(const short8*)&Pw[(i * 16 + lcol) * 64 +
                                    (((half * 4 + quad) ^ (lcol & 7)) * 8)];
      __builtin_amdgcn_s_setprio(1);
      #pragma unroll
      for (int ns = 0; ns < 8; ns++) {
        short8 bfrag = *(const short8*)&Ktc[(ns * 16 + lcol) * 64 +
                                            (((half * 4 + quad) ^ (lcol & 7)) * 8)];
        #pragma unroll
        for (int i = 0; i < 2; i++)
          acco[i][ns] = __builtin_amdgcn_mfma_f32_16x16x32_bf16(pa[i], bfrag, acco[i][ns], 0, 0, 0);
      }
      __builtin_amdgcn_s_setprio(0);
    }
  }

  // reduce row sums across the 16 lcol lanes (once)
  #pragma unroll
  for (int i = 0; i < 2; i++)
    #pragma unroll
    for (int r = 0; r < 4; r++) {
      float s = lsum[i][r];
      #pragma unroll
      for (int off = 1; off < 16; off <<= 1) s += __shfl_xor(s, off, 64);
      lsum[i][r] = 1.f / s;
    }

  // write y
  #pragma unroll
  for (int i = 0; i < 2; i++)
    #pragma unroll
    for (int ns = 0; ns < 8; ns++)
      #pragma unroll
      for (int r = 0; r < 4; r++) {
        int qg = q0 + i * 16 + quad * 4 + r;
        y[(rowbase + qg) * (NH_ * L_) + h * L_ + ns * 16 + lcol] =
            f2bf(acco[i][ns][r] * lsum[i][r]);
      }
}

extern "C" void kernel_launch(void* const* d_in, const int* in_sizes, int n_in,
                              void* d_out, int out_size, void* d_ws, size_t ws_size,
                              hipStream_t stream) {
  const float* x      = (const float*)d_in[0];
  const float* W_lat  = (const float*)d_in[1];
  const float* b_lat  = (const float*)d_in[2];
  const float* W_d    = (const float*)d_in[3];
  const float* b_d    = (const float*)d_in[4];
  const float* W_proj = (const float*)d_in[5];
  const float* b_proj = (const float*)d_in[6];
  float* out = (float*)d_out;

  // workspace layout (bf16 buffers, 16B aligned)
  unsigned short* x_bf   = (unsigned short*)d_ws;                  // [4096][2048]
  unsigned short* BtCat  = x_bf   + (size_t)MTOK * C_;             // [2176][2048]
  unsigned short* WprojT = BtCat  + (size_t)NKQ * C_;              // [2048][2048]
  unsigned short* kqbuf  = WprojT + (size_t)C_ * (NH_ * L_);       // [4096][2176]
  unsigned short* ybuf   = kqbuf  + (size_t)MTOK * NKQ;            // [4096][2048]
  unsigned short* KlT    = ybuf   + (size_t)MTOK * (NH_ * L_);     // [2][128][2048]
  float*          biascat = (float*)(KlT + (size_t)B_ * L_ * T_);  // [2176]

  // 1. merged prep: x->bf16, weight transposes (scale folded), bias concat
  prep_all<<<16649, 256, 0, stream>>>(x, W_lat, W_d, W_proj, b_lat, b_d,
                                      x_bf, BtCat, WprojT, biascat);
  // 2. kq = x @ [W_lat | scale*log2e*W_d] + bias (bf16 out)
  gemm_bt_bias<<<dim3(MTOK / 128, NKQ / 128), 256, 0, stream>>>(
      x_bf, BtCat, biascat, kqbuf, nullptr, MTOK, NKQ, C_);
  // 3. latent transpose for PV staging
  transpose_lat<<<dim3(T_ / 32, L_ / 32, B_), dim3(32, 8), 0, stream>>>(kqbuf, KlT);
  // 4. causal MLA attention (512 balanced blocks, double-buffered)
  attn_mla<<<512, 256, 0, stream>>>(kqbuf, KlT, ybuf);
  // 5. out = y @ W_proj + b_proj (fp32 out)
  gemm_bt_bias<<<dim3(MTOK / 128, C_ / 128), 256, 0, stream>>>(
      ybuf, WprojT, b_proj, nullptr, out, MTOK, C_, C_);
}

// Round 3
// 282.515 us; speedup vs baseline: 1.0920x; 1.0441x over previous
//
#include <hip/hip_runtime.h>
#include <hip/hip_bf16.h>

// Problem constants (B=2, T=2048, C=2048, NH=16, L=128)
#define B_   2
#define T_   2048
#define C_   2048
#define NH_  16
#define L_   128
#define NKQ  2176   // L_ + NH_*L_
#define MTOK 4096   // B_*T_
#define SCALE_ 0.08838834764831845f           // 1/sqrt(128)
#define SCALE2_ 0.12753785792696073f          // SCALE_ * log2(e)

typedef short short8 __attribute__((ext_vector_type(8)));
typedef float f32x4  __attribute__((ext_vector_type(4)));

// async global->LDS, 16B per lane; LDS base must be wave-uniform.
#define GLD16(gp, lp) __builtin_amdgcn_global_load_lds(                      \
    (const __attribute__((address_space(1))) void*)(gp),                     \
    (__attribute__((address_space(3))) void*)(lp), 16, 0, 0)

__device__ __forceinline__ unsigned short f2bf(float f) {
  union { float f; unsigned u; } x; x.f = f;
  unsigned r = x.u + 0x7fffu + ((x.u >> 16) & 1u);   // RNE
  return (unsigned short)(r >> 16);
}

// ---------------- merged prep: cvt + 3 weight transposes + bias concat ----------------
// One dispatch instead of 5 (saves 4 graph launch gaps). Branch is block-uniform.
// grid = 8192 (cvt) + 256 (W_lat) + 4096 (W_d) + 4096 (W_proj) + 9 (bias) = 16649
__global__ __launch_bounds__(256) void prep_all(
    const float* __restrict__ x, const float* __restrict__ W_lat,
    const float* __restrict__ W_d, const float* __restrict__ W_proj,
    const float* __restrict__ b_lat, const float* __restrict__ b_d,
    unsigned short* __restrict__ x_bf, unsigned short* __restrict__ BtCat,
    unsigned short* __restrict__ WprojT, float* __restrict__ biascat) {
  __shared__ float tile[32][33];
  int bid = blockIdx.x;
  const int tid = threadIdx.x;

  if (bid < 8192) {                       // x fp32 -> bf16, 4 elems/thread
    int i = bid * 1024 + tid * 4;
    float4 v = *(const float4*)(x + i);
    ushort4 o;
    o.x = f2bf(v.x); o.y = f2bf(v.y); o.z = f2bf(v.z); o.w = f2bf(v.w);
    *(ushort4*)(x_bf + i) = o;
    return;
  }
  bid -= 8192;

  const float* W; unsigned short* Wt; int K, N; float mul; int nbx;
  if (bid < 256) {                        // W_lat [C][L] -> BtCat[0:L][C]
    W = W_lat; Wt = BtCat; K = C_; N = L_; mul = 1.f; nbx = 4;
  } else if (bid < 256 + 4096) {          // W_d [C][2048] -> BtCat[L:][C], fold scale*log2e
    bid -= 256;
    W = W_d; Wt = BtCat + (size_t)L_ * C_; K = C_; N = NH_ * L_; mul = SCALE2_; nbx = 64;
  } else if (bid < 256 + 8192) {          // W_proj [2048][C] -> WprojT[C][2048]
    bid -= 256 + 4096;
    W = W_proj; Wt = WprojT; K = NH_ * L_; N = C_; mul = 1.f; nbx = 64;
  } else {                                // bias concat [b_lat | scale*log2e*b_d]
    int i = (bid - (256 + 8192)) * 256 + tid;
    if (i < L_) biascat[i] = b_lat[i];
    else if (i < NKQ) biascat[i] = b_d[i - L_] * SCALE2_;
    return;
  }

  const int bx = (bid % nbx) * 32, by = (bid / nbx) * 32;
  const int tx = tid & 31, ty = tid >> 5;
  #pragma unroll
  for (int i2 = 0; i2 < 4; i2++)
    tile[ty + i2 * 8][tx] = W[(size_t)(by + ty + i2 * 8) * N + bx + tx];
  __syncthreads();
  #pragma unroll
  for (int i2 = 0; i2 < 4; i2++)
    Wt[(size_t)(bx + ty + i2 * 8) * K + by + tx] = f2bf(tile[tx][ty + i2 * 8] * mul);
}

// ---- transpose latent cols of kq -> KlT[b][l][t] (bf16) ----
__global__ void transpose_lat(const unsigned short* __restrict__ kq,
                              unsigned short* __restrict__ KlT) {
  __shared__ unsigned short tile[32][33];
  int t0 = blockIdx.x * 32, l0 = blockIdx.y * 32, b = blockIdx.z;
  int tx = threadIdx.x, ty = threadIdx.y;
  #pragma unroll
  for (int i = 0; i < 4; i++)
    tile[ty + i * 8][tx] = kq[((size_t)b * T_ + t0 + ty + i * 8) * NKQ + l0 + tx];
  __syncthreads();
  #pragma unroll
  for (int i = 0; i < 4; i++)
    KlT[((size_t)b * L_ + l0 + ty + i * 8) * T_ + t0 + tx] = tile[tx][ty + i * 8];
}

// ---------------- bf16 MFMA GEMM:  C = A @ Bt^T + bias ----------------
// R6: double-buffered LDS staging (T3-minimum 2-phase, same pattern as attn_mla).
// Old m97-serial structure exposed the stage->vmcnt(0)->barrier drain every
// K-step; at ~2.1 blocks/CU there is too little TLP to hide it (MfmaUtil 20%,
// ~500 TF). Now: prologue stage(0); loop { barrier; stage(kt+1 -> buf^1);
// ds_read+MFMA(buf) } -> the loop-top barrier drains loads issued one full
// compute phase ago, and one barrier per K-step instead of two.
__global__ __launch_bounds__(256) void gemm_bt_bias(
    const unsigned short* __restrict__ A,   // [M][K] bf16
    const unsigned short* __restrict__ Bt,  // [N][K] bf16
    const float* __restrict__ bias,         // [N]
    unsigned short* __restrict__ Cb,        // bf16 out (or null)
    float* __restrict__ Cf,                 // fp32 out (or null)
    int M, int N, int K) {
  __shared__ __align__(16) unsigned short As[2][128 * 32];  // dbuf, BK=32
  __shared__ __align__(16) unsigned short Bs[2][128 * 32];
  const int tid  = threadIdx.x;
  const int wave = tid >> 6, lane = tid & 63;
  const int lcol = lane & 15, quad = lane >> 4;
  const int m0 = blockIdx.x * 128, n0 = blockIdx.y * 128;
  const int wm = (wave >> 1) * 64, wn = (wave & 1) * 64;
  const int lrow = lane >> 2, lchunk = (lane & 3) * 8;
  const int rb = wave * 32;

  f32x4 acc[4][4];
  #pragma unroll
  for (int i = 0; i < 4; i++)
    #pragma unroll
    for (int j = 0; j < 4; j++) acc[i][j] = (f32x4){0.f, 0.f, 0.f, 0.f};

  const int nk = K >> 5;
  // prologue: stage k-tile 0 into buffer 0
  GLD16(&A [(size_t)(m0 + rb      + lrow) * K + lchunk], &As[0][ rb       * 32]);
  GLD16(&A [(size_t)(m0 + rb + 16 + lrow) * K + lchunk], &As[0][(rb + 16) * 32]);
  GLD16(&Bt[(size_t)(n0 + rb      + lrow) * K + lchunk], &Bs[0][ rb       * 32]);
  GLD16(&Bt[(size_t)(n0 + rb + 16 + lrow) * K + lchunk], &Bs[0][(rb + 16) * 32]);

  for (int kt = 0; kt < nk; ++kt) {
    const int cur = kt & 1;
    __syncthreads();  // drains stage(kt) [issued one compute-phase ago] + guards buf reuse

    if (kt + 1 < nk) {  // prefetch next k-tile into the other buffer
      const int kc = (kt + 1) << 5;
      GLD16(&A [(size_t)(m0 + rb      + lrow) * K + kc + lchunk], &As[cur ^ 1][ rb       * 32]);
      GLD16(&A [(size_t)(m0 + rb + 16 + lrow) * K + kc + lchunk], &As[cur ^ 1][(rb + 16) * 32]);
      GLD16(&Bt[(size_t)(n0 + rb      + lrow) * K + kc + lchunk], &Bs[cur ^ 1][ rb       * 32]);
      GLD16(&Bt[(size_t)(n0 + rb + 16 + lrow) * K + kc + lchunk], &Bs[cur ^ 1][(rb + 16) * 32]);
    }

    short8 af[4], bfr[4];
    #pragma unroll
    for (int i = 0; i < 4; i++)
      af[i] = *(const short8*)&As[cur][(wm + i * 16 + lcol) * 32 + quad * 8];
    #pragma unroll
    for (int j = 0; j < 4; j++)
      bfr[j] = *(const short8*)&Bs[cur][(wn + j * 16 + lcol) * 32 + quad * 8];
    #pragma unroll
    for (int i = 0; i < 4; i++)
      #pragma unroll
      for (int j = 0; j < 4; j++)
        acc[i][j] = __builtin_amdgcn_mfma_f32_16x16x32_bf16(af[i], bfr[j], acc[i][j], 0, 0, 0);
  }

  #pragma unroll
  for (int i = 0; i < 4; i++) {
    #pragma unroll
    for (int j = 0; j < 4; j++) {
      int col = n0 + wn + j * 16 + lcol;
      float bv = bias[col];
      #pragma unroll
      for (int r = 0; r < 4; r++) {
        int row = m0 + wm + i * 16 + quad * 4 + r;
        float v = acc[i][j][r] + bv;
        if (Cf) Cf[(size_t)row * N + col] = v;
        else    Cb[(size_t)row * N + col] = f2bf(v);
      }
    }
  }
}

// ---------------- fused causal MLA attention (double-buffered K staging) ----------------
// Block: 4 waves = 4 heads, 32 q-rows. s-tiles of 64, K tiles double-buffered:
//   stage(0); loop: barrier; stage(ts+1 -> other buf); compute(ts)
// so the barrier's vmcnt drain waits on loads issued a full compute-phase ago.
// NOTE (R4 bug): the staging swizzle XOR must use the ACTUAL row&7 of each
// sub-load (rows differ by 4 between kk's) — compute it per kk, don't hoist.
// Grid 512: n<256 heavy tile (63-qi), n>=256 light (qi) -> heavy+light pair per CU.
// No-max softmax; scale*log2e folded into q; exp via v_exp2.
// R5: softmax+PV split by s-halves (VALU of half-1 overlaps PV MFMA of half-0);
// s_setprio(1) around MFMA clusters (T5).
__global__ __launch_bounds__(256, 2) void attn_mla(
    const unsigned short* __restrict__ kq,   // [B*T][NKQ]
    const unsigned short* __restrict__ KlT,  // [B][L][T]
    unsigned short* __restrict__ y) {        // [B*T][NH*L]
  __shared__ __align__(16) unsigned short Kr[2][64 * 128];   // [s][l] swizzled
  __shared__ __align__(16) unsigned short Kt[2][128 * 64];   // [l][s] swizzled
  __shared__ __align__(16) unsigned short Pls[4][32 * 64];   // per-wave P, swizzled

  const int tid  = threadIdx.x;
  const int wave = tid >> 6, lane = tid & 63;
  const int lcol = lane & 15, quad = lane >> 4;
  const int n    = blockIdx.x;
  const int slot = n >> 8, c = n & 255;
  const int hg   = c >> 5, qi = c & 31;
  const int b    = hg >> 2;
  const int h    = (hg & 3) * 4 + wave;
  const int qt32 = slot ? qi : (63 - qi);    // 32-row q-tile index
  const size_t rowbase = (size_t)b * T_;
  const int q0 = qt32 * 32;
  unsigned short* Pw = &Pls[wave][0];

  // Q fragments (A-layout m=lane&15, k=quad*8+j); scale*log2e pre-folded
  short8 qf[2][4];
  #pragma unroll
  for (int i = 0; i < 2; i++) {
    const unsigned short* qp = kq + (rowbase + q0 + i * 16 + lcol) * NKQ + L_ + h * L_;
    #pragma unroll
    for (int kc = 0; kc < 4; kc++)
      qf[i][kc] = *(const short8*)(qp + kc * 32 + quad * 8);
  }

  f32x4 acco[2][8];
  #pragma unroll
  for (int i = 0; i < 2; i++)
    #pragma unroll
    for (int ns = 0; ns < 8; ns++) acco[i][ns] = (f32x4){0.f, 0.f, 0.f, 0.f};
  float lsum[2][4];
  #pragma unroll
  for (int i = 0; i < 2; i++)
    #pragma unroll
    for (int r = 0; r < 4; r++) lsum[i][r] = 0.f;

  const int nt = (qt32 >> 1) + 1;

  // prologue: stage tile 0 into buffer 0 (swizzle computed per sub-load!)
  #pragma unroll
  for (int kk = 0; kk < 4; kk++) {
    int r0 = wave * 16 + kk * 4;
    int rg = r0 + (lane >> 4);
    int cl = ((lane & 15) ^ (rg & 7)) * 8;
    GLD16(kq + (rowbase + rg) * NKQ + cl, &Kr[0][r0 * 128]);
  }
  #pragma unroll
  for (int kk = 0; kk < 4; kk++) {
    int r0 = wave * 32 + kk * 8;
    int rg = r0 + (lane >> 3);
    int cl = ((lane & 7) ^ (rg & 7)) * 8;
    GLD16(KlT + ((size_t)b * L_ + rg) * T_ + cl, &Kt[0][r0 * 64]);
  }

  for (int ts = 0; ts < nt; ts++) {
    const int cur = ts & 1;
    __syncthreads();  // drains stage(ts) [issued one full phase ago] + guards buf reuse

    if (ts + 1 < nt) {  // prefetch next tile into the other buffer
      const int s1 = (ts + 1) * 64;
      #pragma unroll
      for (int kk = 0; kk < 4; kk++) {
        int r0 = wave * 16 + kk * 4;
        int rg = r0 + (lane >> 4);
        int cl = ((lane & 15) ^ (rg & 7)) * 8;
        GLD16(kq + (rowbase + s1 + rg) * NKQ + cl, &Kr[cur ^ 1][r0 * 128]);
      }
      #pragma unroll
      for (int kk = 0; kk < 4; kk++) {
        int r0 = wave * 32 + kk * 8;
        int rg = r0 + (lane >> 3);
        int cl = ((lane & 7) ^ (rg & 7)) * 8;
        GLD16(KlT + ((size_t)b * L_ + rg) * T_ + s1 + cl, &Kt[cur ^ 1][r0 * 64]);
      }
    }

    const unsigned short* Krc = &Kr[cur][0];
    const unsigned short* Ktc = &Kt[cur][0];

    // S(32x64) = Q @ K^T
    f32x4 accs[2][4];
    #pragma unroll
    for (int i = 0; i < 2; i++)
      #pragma unroll
      for (int ns = 0; ns < 4; ns++) accs[i][ns] = (f32x4){0.f, 0.f, 0.f, 0.f};
    __builtin_amdgcn_s_setprio(1);
    #pragma unroll
    for (int kc = 0; kc < 4; kc++)
      #pragma unroll
      for (int ns = 0; ns < 4; ns++) {
        short8 bfrag = *(const short8*)&Krc[(ns * 16 + lcol) * 128 +
                                            (((kc * 4 + quad) ^ (lcol & 7)) * 8)];
        #pragma unroll
        for (int i = 0; i < 2; i++)
          accs[i][ns] = __builtin_amdgcn_mfma_f32_16x16x32_bf16(qf[i][kc], bfrag, accs[i][ns], 0, 0, 0);
      }
    __builtin_amdgcn_s_setprio(0);

    // p = 2^s (log2e folded); truncate to bf16, lsum from truncated value.
    // Split into s-halves: softmax(half) then PV(kc2=half) — half-1 VALU overlaps
    // half-0's PV MFMA drain (separate pipes), and the P->pa lgkm wait shortens.
    const bool diag = (ts == nt - 1);
    #pragma unroll
    for (int half = 0; half < 2; half++) {
      #pragma unroll
      for (int i = 0; i < 2; i++)
        #pragma unroll
        for (int n2 = 0; n2 < 2; n2++) {
          const int ns = half * 2 + n2;
          #pragma unroll
          for (int r = 0; r < 4; r++) {
            float v = accs[i][ns][r];
            int sg = ns * 16 + lcol;
            int qg = (qt32 & 1) * 32 + i * 16 + quad * 4 + r;
            if (diag && sg > qg) v = -1e30f;
            float e = __builtin_amdgcn_exp2f(v);
            unsigned eu = __float_as_uint(e) & 0xffff0000u;
            lsum[i][r] += __uint_as_float(eu);
            int row = i * 16 + quad * 4 + r;
            int col = ns * 16 + lcol;
            int phys = ((col >> 3) ^ (row & 7));
            Pw[row * 64 + phys * 8 + (col & 7)] = (unsigned short)(eu >> 16);
          }
        }

      // O(32x128) += P(32x[half]) @ K([half]x128)   (Pw wave-private: no barrier)
      short8 pa[2];
      #pragma unroll
      for (int i = 0; i < 2; i++)
        pa[i] = *(const short8*)&Pw[(i * 16 + lcol) * 64 +
                                    (((half * 4 + quad) ^ (lcol & 7)) * 8)];
      __builtin_amdgcn_s_setprio(1);
      #pragma unroll
      for (int ns = 0; ns < 8; ns++) {
        short8 bfrag = *(const short8*)&Ktc[(ns * 16 + lcol) * 64 +
                                            (((half * 4 + quad) ^ (lcol & 7)) * 8)];
        #pragma unroll
        for (int i = 0; i < 2; i++)
          acco[i][ns] = __builtin_amdgcn_mfma_f32_16x16x32_bf16(pa[i], bfrag, acco[i][ns], 0, 0, 0);
      }
      __builtin_amdgcn_s_setprio(0);
    }
  }

  // reduce row sums across the 16 lcol lanes (once)
  #pragma unroll
  for (int i = 0; i < 2; i++)
    #pragma unroll
    for (int r = 0; r < 4; r++) {
      float s = lsum[i][r];
      #pragma unroll
      for (int off = 1; off < 16; off <<= 1) s += __shfl_xor(s, off, 64);
      lsum[i][r] = 1.f / s;
    }

  // write y
  #pragma unroll
  for (int i = 0; i < 2; i++)
    #pragma unroll
    for (int ns = 0; ns < 8; ns++)
      #pragma unroll
      for (int r = 0; r < 4; r++) {
        int qg = q0 + i * 16 + quad * 4 + r;
        y[(rowbase + qg) * (NH_ * L_) + h * L_ + ns * 16 + lcol] =
            f2bf(acco[i][ns][r] * lsum[i][r]);
      }
}

extern "C" void kernel_launch(void* const* d_in, const int* in_sizes, int n_in,
                              void* d_out, int out_size, void* d_ws, size_t ws_size,
                              hipStream_t stream) {
  const float* x      = (const float*)d_in[0];
  const float* W_lat  = (const float*)d_in[1];
  const float* b_lat  = (const float*)d_in[2];
  const float* W_d    = (const float*)d_in[3];
  const float* b_d    = (const float*)d_in[4];
  const float* W_proj = (const float*)d_in[5];
  const float* b_proj = (const float*)d_in[6];
  float* out = (float*)d_out;

  // workspace layout (bf16 buffers, 16B aligned)
  unsigned short* x_bf   = (unsigned short*)d_ws;                  // [4096][2048]
  unsigned short* BtCat  = x_bf   + (size_t)MTOK * C_;             // [2176][2048]
  unsigned short* WprojT = BtCat  + (size_t)NKQ * C_;              // [2048][2048]
  unsigned short* kqbuf  = WprojT + (size_t)C_ * (NH_ * L_);       // [4096][2176]
  unsigned short* ybuf   = kqbuf  + (size_t)MTOK * NKQ;            // [4096][2048]
  unsigned short* KlT    = ybuf   + (size_t)MTOK * (NH_ * L_);     // [2][128][2048]
  float*          biascat = (float*)(KlT + (size_t)B_ * L_ * T_);  // [2176]

  // 1. merged prep: x->bf16, weight transposes (scale folded), bias concat
  prep_all<<<16649, 256, 0, stream>>>(x, W_lat, W_d, W_proj, b_lat, b_d,
                                      x_bf, BtCat, WprojT, biascat);
  // 2. kq = x @ [W_lat | scale*log2e*W_d] + bias (bf16 out)
  gemm_bt_bias<<<dim3(MTOK / 128, NKQ / 128), 256, 0, stream>>>(
      x_bf, BtCat, biascat, kqbuf, nullptr, MTOK, NKQ, C_);
  // 3. latent transpose for PV staging
  transpose_lat<<<dim3(T_ / 32, L_ / 32, B_), dim3(32, 8), 0, stream>>>(kqbuf, KlT);
  // 4. causal MLA attention (512 balanced blocks, double-buffered)
  attn_mla<<<512, 256, 0, stream>>>(kqbuf, KlT, ybuf);
  // 5. out = y @ W_proj + b_proj (fp32 out)
  gemm_bt_bias<<<dim3(MTOK / 128, C_ / 128), 256, 0, stream>>>(
      ybuf, WprojT, b_proj, nullptr, out, MTOK, C_, C_);
}